// Round 4
// baseline (459.562 us; speedup 1.0000x reference)
//
#include <hip/hip_runtime.h>
#include <stdint.h>

typedef unsigned short u16t;
typedef unsigned int   u32t;
typedef __attribute__((ext_vector_type(8))) short frag8;   // 8 bf16 = 4 VGPRs
typedef __attribute__((ext_vector_type(4))) float fragc;   // 4 fp32 acc

#define NN 50000
#define NE 800000

// packed-weight offsets in u16 elements within d_ws (total 69632 u16 = 139264 B)
#define W1P 0
#define W2P 24576
#define W3P 40960
#define U1P 49152
#define U2P 61440

#define XST 200   // edge X tile row stride (192 + 8 pad) in bf16
#define HST 136   // hidden tile row stride (128 + 8 pad)
#define XSTN 104  // node X tile row stride (96 + 8 pad)

__device__ __forceinline__ u16t f2bf(float f) {
    u32t x = __builtin_bit_cast(u32t, f);
    x = x + 0x7FFFu + ((x >> 16) & 1u);   // RNE
    return (u16t)(x >> 16);
}

// ---------------------------------------------------------------------------
// Prepack: W (K x N row-major, fp32) -> bf16 B-fragment order for
// mfma_f32_16x16x32_bf16. Fragment id = (nb*ksteps + ks); lane holds
// W[ks*32 + (lane>>4)*8 + j][nb*16 + (lane&15)], j=0..7, packed 16 B/lane.
// ---------------------------------------------------------------------------
__global__ void prepack_k(const float* __restrict__ w1, const float* __restrict__ w2,
                          const float* __restrict__ w3, const float* __restrict__ u1,
                          const float* __restrict__ u2, u16t* __restrict__ out) {
    int t = blockIdx.x * blockDim.x + threadIdx.x;
    const float* src; u16t* dst; int id, K, N;
    if (t < 3072)      { id = t;        K = 192; N = 128; src = w1; dst = out + W1P; }
    else if (t < 5120) { id = t - 3072; K = 128; N = 128; src = w2; dst = out + W2P; }
    else if (t < 6144) { id = t - 5120; K = 128; N = 64;  src = w3; dst = out + W3P; }
    else if (t < 7680) { id = t - 6144; K = 96;  N = 128; src = u1; dst = out + U1P; }
    else if (t < 8704) { id = t - 7680; K = 128; N = 64;  src = u2; dst = out + U2P; }
    else return;
    int lane = id & 63;
    int fl   = id >> 6;
    int ksteps = K >> 5;
    int nb = fl / ksteps, ks = fl - nb * ksteps;
    int n  = nb * 16 + (lane & 15);
    int k0 = ks * 32 + (lane >> 4) * 8;
    const float* s = src + (size_t)k0 * N + n;
    uint4 v;
    v.x = (u32t)f2bf(s[0])           | ((u32t)f2bf(s[(size_t)N])   << 16);
    v.y = (u32t)f2bf(s[2*(size_t)N]) | ((u32t)f2bf(s[3*(size_t)N]) << 16);
    v.z = (u32t)f2bf(s[4*(size_t)N]) | ((u32t)f2bf(s[5*(size_t)N]) << 16);
    v.w = (u32t)f2bf(s[6*(size_t)N]) | ((u32t)f2bf(s[7*(size_t)N]) << 16);
    *(uint4*)(dst + (size_t)id * 8) = v;
}

// ---------------------------------------------------------------------------
// Edge kernel: 64 edges/block, 256 threads (4 waves x 16 rows).
// X = [nf[src] | nf[dst] | ef | st[src]] (192 cols, fp32 -> bf16 in staging),
// MLP 192->128->128->64 via MFMA, fp32 atomic scatter-add into out1[dst].
// ---------------------------------------------------------------------------
__global__ __launch_bounds__(256)
void edge_k(const float* __restrict__ nf, const float* __restrict__ ef,
            const float* __restrict__ st, const float* __restrict__ b1,
            const float* __restrict__ b2, const float* __restrict__ b3,
            const int* __restrict__ eidx, const u16t* __restrict__ wp,
            float* __restrict__ out1) {
    __shared__ __align__(16) u16t X[64 * XST];   // 25600 B
    __shared__ __align__(16) u16t H[64 * HST];   // 17408 B
    const int tid = threadIdx.x;
    const int e0  = blockIdx.x * 64;

    { // zero-init LDS (covers pads; defensive)
        uint4 z = make_uint4(0u, 0u, 0u, 0u);
        uint4* xp = (uint4*)X;
        uint4* hp = (uint4*)H;
        for (int c = tid; c < 1600; c += 256) xp[c] = z;
        for (int c = tid; c < 1088; c += 256) hp[c] = z;
    }
    __syncthreads();

    { // stage X tile: 4 threads/edge, 12 float4 groups each (48 groups/row)
        int el = tid >> 2, p = tid & 3;
        int e = e0 + el;
        int s = eidx[2 * e], d = eidx[2 * e + 1];
        const float4* ns  = (const float4*)(nf + (size_t)s * 64);
        const float4* ndp = (const float4*)(nf + (size_t)d * 64);
        const float4* epf = (const float4*)(ef + (size_t)e * 32);
        const float4* sp  = (const float4*)(st + (size_t)s * 32);
        u16t* xr = X + el * XST;
        #pragma unroll
        for (int g = p; g < 48; g += 4) {
            float4 v;
            if (g < 16)      v = ns[g];
            else if (g < 32) v = ndp[g - 16];
            else if (g < 40) v = epf[g - 32];
            else             v = sp[g - 40];
            uint2 pk;
            pk.x = (u32t)f2bf(v.x) | ((u32t)f2bf(v.y) << 16);
            pk.y = (u32t)f2bf(v.z) | ((u32t)f2bf(v.w) << 16);
            *(uint2*)(xr + g * 4) = pk;   // 8 B store, 8 B aligned
        }
    }
    __syncthreads();

    const int lane = tid & 63;
    const int wv   = tid >> 6;
    const int m16  = wv * 16;
    const int lr   = lane & 15;
    const int qd   = lane >> 4;

    // ---- layer 1: X(64x192) @ W1(192x128), ReLU
    fragc acc[8];
    #pragma unroll
    for (int n = 0; n < 8; n++) acc[n] = (fragc){0.f, 0.f, 0.f, 0.f};
    {
        const frag8* w = (const frag8*)(wp + W1P);
        #pragma unroll
        for (int ks = 0; ks < 6; ks++) {
            frag8 a = *(const frag8*)(X + (m16 + lr) * XST + ks * 32 + qd * 8);
            #pragma unroll
            for (int n = 0; n < 8; n++)
                acc[n] = __builtin_amdgcn_mfma_f32_16x16x32_bf16(
                    a, w[(n * 6 + ks) * 64 + lane], acc[n], 0, 0, 0);
        }
    }
    #pragma unroll
    for (int n = 0; n < 8; n++) {
        float bs = b1[n * 16 + lr];
        #pragma unroll
        for (int r = 0; r < 4; r++) {
            float v = acc[n][r] + bs;
            H[(m16 + qd * 4 + r) * HST + n * 16 + lr] = f2bf(v > 0.f ? v : 0.f);
        }
    }
    __syncthreads();

    // ---- layer 2: H(64x128) @ W2(128x128), ReLU
    #pragma unroll
    for (int n = 0; n < 8; n++) acc[n] = (fragc){0.f, 0.f, 0.f, 0.f};
    {
        const frag8* w = (const frag8*)(wp + W2P);
        #pragma unroll
        for (int ks = 0; ks < 4; ks++) {
            frag8 a = *(const frag8*)(H + (m16 + lr) * HST + ks * 32 + qd * 8);
            #pragma unroll
            for (int n = 0; n < 8; n++)
                acc[n] = __builtin_amdgcn_mfma_f32_16x16x32_bf16(
                    a, w[(n * 4 + ks) * 64 + lane], acc[n], 0, 0, 0);
        }
    }
    __syncthreads();   // all H reads complete before overwrite
    #pragma unroll
    for (int n = 0; n < 8; n++) {
        float bs = b2[n * 16 + lr];
        #pragma unroll
        for (int r = 0; r < 4; r++) {
            float v = acc[n][r] + bs;
            H[(m16 + qd * 4 + r) * HST + n * 16 + lr] = f2bf(v > 0.f ? v : 0.f);
        }
    }
    __syncthreads();

    // ---- layer 3: H(64x128) @ W3(128x64), no activation
    fragc a3[4];
    #pragma unroll
    for (int n = 0; n < 4; n++) a3[n] = (fragc){0.f, 0.f, 0.f, 0.f};
    {
        const frag8* w = (const frag8*)(wp + W3P);
        #pragma unroll
        for (int ks = 0; ks < 4; ks++) {
            frag8 a = *(const frag8*)(H + (m16 + lr) * HST + ks * 32 + qd * 8);
            #pragma unroll
            for (int n = 0; n < 4; n++)
                a3[n] = __builtin_amdgcn_mfma_f32_16x16x32_bf16(
                    a, w[(n * 4 + ks) * 64 + lane], a3[n], 0, 0, 0);
        }
    }
    // scatter-add messages: lane's rows are edges e0+m16+qd*4+r, cols n*16+lr
    int ds[4];
    #pragma unroll
    for (int r = 0; r < 4; r++) ds[r] = eidx[2 * (e0 + m16 + qd * 4 + r) + 1];
    #pragma unroll
    for (int n = 0; n < 4; n++) {
        float bs = b3[n * 16 + lr];
        #pragma unroll
        for (int r = 0; r < 4; r++)
            atomicAdd(out1 + (size_t)ds[r] * 64 + n * 16 + lr, a3[n][r] + bs);
    }
}

// ---------------------------------------------------------------------------
// Node kernel: 64 nodes/block; upd = relu([nf|st] @ uW1 + ub1) @ uW2 + ub2;
// out0 = nf + upd (fp32).
// ---------------------------------------------------------------------------
__global__ __launch_bounds__(256)
void node_k(const float* __restrict__ nf, const float* __restrict__ st,
            const float* __restrict__ b1, const float* __restrict__ b2,
            const u16t* __restrict__ wp, float* __restrict__ out) {
    __shared__ __align__(16) u16t X[64 * XSTN];  // 13312 B
    __shared__ __align__(16) u16t H[64 * HST];   // 17408 B
    const int tid = threadIdx.x;
    const int n0  = blockIdx.x * 64;

    { // zero-init LDS
        uint4 z = make_uint4(0u, 0u, 0u, 0u);
        uint4* xp = (uint4*)X;
        uint4* hp = (uint4*)H;
        for (int c = tid; c < 832;  c += 256) xp[c] = z;
        for (int c = tid; c < 1088; c += 256) hp[c] = z;
    }
    __syncthreads();

    { // stage: 4 threads/row, 6 float4 groups each (24 groups/row = 96 cols)
        int rl = tid >> 2, p = tid & 3;
        int nd = n0 + rl;
        const float4* ns = (const float4*)(nf + (size_t)nd * 64);
        const float4* sp = (const float4*)(st + (size_t)nd * 32);
        u16t* xr = X + rl * XSTN;
        #pragma unroll
        for (int g = p; g < 24; g += 4) {
            float4 v = make_float4(0.f, 0.f, 0.f, 0.f);
            if (nd < NN) v = (g < 16) ? ns[g] : sp[g - 16];
            uint2 pk;
            pk.x = (u32t)f2bf(v.x) | ((u32t)f2bf(v.y) << 16);
            pk.y = (u32t)f2bf(v.z) | ((u32t)f2bf(v.w) << 16);
            *(uint2*)(xr + g * 4) = pk;
        }
    }
    __syncthreads();
    const int lane = tid & 63;
    const int wv   = tid >> 6;
    const int m16  = wv * 16;
    const int lr   = lane & 15;
    const int qd   = lane >> 4;

    fragc acc[8];
    #pragma unroll
    for (int n = 0; n < 8; n++) acc[n] = (fragc){0.f, 0.f, 0.f, 0.f};
    {
        const frag8* w = (const frag8*)(wp + U1P);
        #pragma unroll
        for (int ks = 0; ks < 3; ks++) {
            frag8 a = *(const frag8*)(X + (m16 + lr) * XSTN + ks * 32 + qd * 8);
            #pragma unroll
            for (int n = 0; n < 8; n++)
                acc[n] = __builtin_amdgcn_mfma_f32_16x16x32_bf16(
                    a, w[(n * 3 + ks) * 64 + lane], acc[n], 0, 0, 0);
        }
    }
    #pragma unroll
    for (int n = 0; n < 8; n++) {
        float bs = b1[n * 16 + lr];
        #pragma unroll
        for (int r = 0; r < 4; r++) {
            float v = acc[n][r] + bs;
            H[(m16 + qd * 4 + r) * HST + n * 16 + lr] = f2bf(v > 0.f ? v : 0.f);
        }
    }
    __syncthreads();

    fragc a2[4];
    #pragma unroll
    for (int n = 0; n < 4; n++) a2[n] = (fragc){0.f, 0.f, 0.f, 0.f};
    {
        const frag8* w = (const frag8*)(wp + U2P);
        #pragma unroll
        for (int ks = 0; ks < 4; ks++) {
            frag8 a = *(const frag8*)(H + (m16 + lr) * HST + ks * 32 + qd * 8);
            #pragma unroll
            for (int n = 0; n < 4; n++)
                a2[n] = __builtin_amdgcn_mfma_f32_16x16x32_bf16(
                    a, w[(n * 4 + ks) * 64 + lane], a2[n], 0, 0, 0);
        }
    }
    #pragma unroll
    for (int n = 0; n < 4; n++) {
        float bs = b2[n * 16 + lr];
        #pragma unroll
        for (int r = 0; r < 4; r++) {
            int nd = n0 + m16 + qd * 4 + r;
            if (nd < NN) {
                int col = n * 16 + lr;
                out[(size_t)nd * 64 + col] = nf[(size_t)nd * 64 + col] + a2[n][r] + bs;
            }
        }
    }
}

extern "C" void kernel_launch(void* const* d_in, const int* in_sizes, int n_in,
                              void* d_out, int out_size, void* d_ws, size_t ws_size,
                              hipStream_t stream) {
    const float* nf  = (const float*)d_in[0];
    const float* ef  = (const float*)d_in[1];
    const float* st  = (const float*)d_in[2];
    const float* mW1 = (const float*)d_in[3];
    const float* mb1 = (const float*)d_in[4];
    const float* mW2 = (const float*)d_in[5];
    const float* mb2 = (const float*)d_in[6];
    const float* mW3 = (const float*)d_in[7];
    const float* mb3 = (const float*)d_in[8];
    const float* uW1 = (const float*)d_in[9];
    const float* ub1 = (const float*)d_in[10];
    const float* uW2 = (const float*)d_in[11];
    const float* ub2 = (const float*)d_in[12];
    const int*  eidx = (const int*)d_in[13];

    float* out0 = (float*)d_out;               // NN*64 fp32
    float* out1 = out0 + (size_t)NN * 64;      // NN*64 fp32 (aggregated)
    u16t*  wp   = (u16t*)d_ws;                 // packed bf16 weights, 139264 B

    hipMemsetAsync(out1, 0, (size_t)NN * 64 * 4, stream);
    prepack_k<<<34, 256, 0, stream>>>(mW1, mW2, mW3, uW1, uW2, wp);
    edge_k<<<NE / 64, 256, 0, stream>>>(nf, ef, st, mb1, mb2, mb3, eidx, wp, out1);
    node_k<<<(NN + 63) / 64, 256, 0, stream>>>(nf, st, ub1, ub2, wp, out0);
}